// Round 2
// baseline (97.506 us; speedup 1.0000x reference)
//
#include <hip/hip_runtime.h>
#include <stdint.h>

// Galerkin self-attention, fused:
//   out = seq @ (wq.T @ blockdiag_h(kv[b,h]) @ wo.T) + bo
//   kv[b,h] = (1/S) * LN(k)_h^T @ LN(v)_h,   k = seq@wk.T, v = seq@wv.T
// v2: no atomics (per-tile bf16 kv partials streamed into d_out-as-scratch,
//     reduced by gka_red), no weight LDS staging (weights read from L2),
//     32KB LDS per block.
// ws layout (bytes):
//   0        wk bf16 [256][256]
//   131072   wv bf16 [256][256]
//   262144   wqT bf16 [256 i][256 j]   (wq transposed)
//   393216   wo bf16 [256 o][256 j]
//   524288   kv  f32 [4 b][4 h][64 d][64 e]   (written by gka_red)
//   786432   M1T bf16 [4 b][256 o][256 j]
//   1310720  WcT bf16 [4 b][256 o][256 i]
//   total 1835008 bytes
// d_out doubles as scratch for P = bf16 partials [4 b][128 p][4 h][64 d][64 e]
// (16.8MB of the 33.5MB output buffer); gka_out fully overwrites d_out last.

#define EMBED 256
#define SEQ   8192
#define LN_EPS 1e-5f

using bf16x8 = __attribute__((ext_vector_type(8))) short;
using bf16x4 = __attribute__((ext_vector_type(4))) short;
using f32x4  = __attribute__((ext_vector_type(4))) float;

static __device__ __forceinline__ short f2bf(float f) {
  uint32_t x = __float_as_uint(f);
  uint32_t r = x + 0x7fffu + ((x >> 16) & 1u);   // RNE
  return (short)(r >> 16);
}
static __device__ __forceinline__ float bf2f(unsigned short u) {
  return __uint_as_float((uint32_t)u << 16);
}

#define MFMA16(a, b, c) __builtin_amdgcn_mfma_f32_16x16x32_bf16((a), (b), (c), 0, 0, 0)

// Stage 64x256 fp32 rows -> bf16 LDS [64][256], rows 512B, swizzled byte^=(row&7)<<4
static __device__ __forceinline__ void stage_x(char* smem, const float* __restrict__ src, int tid) {
#pragma unroll
  for (int i = 0; i < 8; ++i) {
    int g = tid + i * 256;              // 16B-granule index, 2048 total
    int row = g >> 5, c16 = g & 31;
    const f32x4* p = (const f32x4*)(src + row * EMBED + c16 * 8);
    f32x4 f0 = p[0], f1 = p[1];
    bf16x8 v;
    v[0] = f2bf(f0[0]); v[1] = f2bf(f0[1]); v[2] = f2bf(f0[2]); v[3] = f2bf(f0[3]);
    v[4] = f2bf(f1[0]); v[5] = f2bf(f1[1]); v[6] = f2bf(f1[2]); v[7] = f2bf(f1[3]);
    *(bf16x8*)(smem + row * 512 + ((c16 * 16) ^ ((row & 7) << 4))) = v;
  }
}

// ---------------- prep: weights -> bf16 (wq transposed) ----------------
__global__ void gka_prep(const float* __restrict__ wq, const float* __restrict__ wk,
                         const float* __restrict__ wv, const float* __restrict__ wo,
                         unsigned short* __restrict__ wkb, unsigned short* __restrict__ wvb,
                         unsigned short* __restrict__ wqt, unsigned short* __restrict__ wob) {
  int gid = blockIdx.x * 256 + threadIdx.x;   // grid 1024*256 = 4*65536
  int m = gid >> 16, e = gid & 65535;
  if (m == 0)      { wkb[e] = f2bf(wk[e]); }
  else if (m == 1) { wvb[e] = f2bf(wv[e]); }
  else if (m == 2) { int i = e >> 8, j = e & 255; wqt[e] = f2bf(wq[j * 256 + i]); }
  else             { wob[e] = f2bf(wo[e]); }
}

// ---------------- pass A: k,v GEMM + per-head LN + per-tile kv partial ----------------
__global__ __launch_bounds__(256, 2)
void gka_kv(const float* __restrict__ seq,
            const unsigned short* __restrict__ wkb, const unsigned short* __restrict__ wvb,
            const float* __restrict__ lkg, const float* __restrict__ lkb,
            const float* __restrict__ lvg, const float* __restrict__ lvb,
            unsigned short* __restrict__ P) {
  __shared__ char smem[32768];            // x-tile, later reused for kT/vT
  const int tid = threadIdx.x;
  const int lane = tid & 63;
  const int wid = tid >> 6;               // wave = head
  const int l15 = lane & 15, l4 = lane >> 4, l7 = lane & 7;
  const int tile = blockIdx.x;            // 512 blocks, 64 tokens each
  const int b = tile >> 7;
  const int ptile = tile & 127;
  const int srow = ptile * 64;

  stage_x(smem, seq + (size_t)(b * SEQ + srow) * EMBED, tid);
  __syncthreads();

  bf16x4 kln[16], vln[16];                // packed LN'd frags [m*4+n], 4 tokens each
  f32x4 acc[4][4];

#pragma unroll
  for (int mat = 0; mat < 2; ++mat) {
    const unsigned short* W = mat ? wvb : wkb;
    const float* gp = mat ? lvg : lkg;
    const float* bp = mat ? lvb : lkb;
    float gv[4], bv[4];
#pragma unroll
    for (int n = 0; n < 4; ++n) { gv[n] = gp[n * 16 + l15]; bv[n] = bp[n * 16 + l15]; }
#pragma unroll
    for (int m = 0; m < 4; ++m)
#pragma unroll
      for (int n = 0; n < 4; ++n) acc[m][n] = (f32x4)0.0f;

#pragma unroll
    for (int kk = 0; kk < 8; ++kk) {      // K = 256, steps of 32; no barriers
      bf16x8 af[4], bw[4];
#pragma unroll
      for (int m = 0; m < 4; ++m) {
        int row = m * 16 + l15;
        af[m] = *(const bf16x8*)(smem + row * 512 + ((kk * 64 + l4 * 16) ^ (l7 << 4)));
      }
#pragma unroll
      for (int n = 0; n < 4; ++n) {
        int row = wid * 64 + n * 16 + l15;     // weight row j (L2-resident)
        bw[n] = *(const bf16x8*)(W + row * 256 + kk * 32 + l4 * 8);
      }
#pragma unroll
      for (int m = 0; m < 4; ++m)
#pragma unroll
        for (int n = 0; n < 4; ++n)
          acc[m][n] = MFMA16(af[m], bw[n], acc[m][n]);
    }

    // LayerNorm over this wave's 64 head-cols, per token row
#pragma unroll
    for (int m = 0; m < 4; ++m) {
      float mu[4], rs[4];
#pragma unroll
      for (int r = 0; r < 4; ++r) {
        float s1 = 0.f, s2 = 0.f;
#pragma unroll
        for (int n = 0; n < 4; ++n) { float x = acc[m][n][r]; s1 += x; s2 += x * x; }
#pragma unroll
        for (int msk = 1; msk < 16; msk <<= 1) {
          s1 += __shfl_xor(s1, msk);
          s2 += __shfl_xor(s2, msk);
        }
        mu[r] = s1 * (1.f / 64.f);
        float var = s2 * (1.f / 64.f) - mu[r] * mu[r];
        rs[r] = rsqrtf(var + LN_EPS);
      }
#pragma unroll
      for (int n = 0; n < 4; ++n) {
        bf16x4 pk;
#pragma unroll
        for (int r = 0; r < 4; ++r)
          pk[r] = f2bf((acc[m][n][r] - mu[r]) * rs[r] * gv[n] + bv[n]);
        if (mat == 0) kln[m * 4 + n] = pk; else vln[m * 4 + n] = pk;
      }
    }
  }

  __syncthreads();                        // all x-tile reads done; reuse smem
  // kv partial: two phases, heads {0,1} then {2,3}
  // LDS slots: [kT0 8K][vT0 8K][kT1 8K][vT1 8K], rows [d][64 s] 128B swizzled
#pragma unroll
  for (int p = 0; p < 2; ++p) {
    if ((wid >> 1) == p) {
      int hs = wid & 1;
#pragma unroll
      for (int m = 0; m < 4; ++m)
#pragma unroll
        for (int n = 0; n < 4; ++n) {
          int d = n * 16 + l15;
          int sb = m * 32 + l4 * 8;       // byte in row, s0 = m*16 + l4*4
          int off = hs * 16384 + d * 128 + (sb ^ (l7 << 4));
          *(bf16x4*)(smem + off) = kln[m * 4 + n];
          *(bf16x4*)(smem + off + 8192) = vln[m * 4 + n];
        }
    }
    __syncthreads();
    int hs = wid >> 1;                    // head slot this wave computes
    int feh = wid & 1;                    // e-half
    f32x4 kvacc[4][2];
#pragma unroll
    for (int fd = 0; fd < 4; ++fd) { kvacc[fd][0] = (f32x4)0.0f; kvacc[fd][1] = (f32x4)0.0f; }
#pragma unroll
    for (int kk = 0; kk < 2; ++kk) {      // 64 tokens = 2 K-steps
      bf16x8 a2[4], b2[2];
#pragma unroll
      for (int fd = 0; fd < 4; ++fd) {
        int row = fd * 16 + l15;
        a2[fd] = *(const bf16x8*)(smem + hs * 16384 + row * 128 +
                                  ((kk * 64 + l4 * 16) ^ (l7 << 4)));
      }
#pragma unroll
      for (int c = 0; c < 2; ++c) {
        int row = (feh * 2 + c) * 16 + l15;
        b2[c] = *(const bf16x8*)(smem + hs * 16384 + 8192 + row * 128 +
                                 ((kk * 64 + l4 * 16) ^ (l7 << 4)));
      }
#pragma unroll
      for (int fd = 0; fd < 4; ++fd)
#pragma unroll
        for (int c = 0; c < 2; ++c)
          kvacc[fd][c] = MFMA16(a2[fd], b2[c], kvacc[fd][c]);
    }
    int hg = p * 2 + hs;
    unsigned short* Ph = P + (((size_t)(b * 128 + ptile) * 4 + hg) << 12);
#pragma unroll
    for (int fd = 0; fd < 4; ++fd)
#pragma unroll
      for (int c = 0; c < 2; ++c)
#pragma unroll
        for (int r = 0; r < 4; ++r) {
          int d = fd * 16 + l4 * 4 + r;
          int e = (feh * 2 + c) * 16 + l15;
          Ph[d * 64 + e] = (unsigned short)f2bf(kvacc[fd][c][r]);
        }
    __syncthreads();                      // before phase-1 overwrites LDS
  }
}

// ---------------- reduce: kv[b,h,d,e] = sum_p P[b,p,h,d,e] ----------------
__global__ __launch_bounds__(256)
void gka_red(const unsigned short* __restrict__ P, float* __restrict__ kv) {
  int idx = blockIdx.x * 256 + threadIdx.x;   // 65536 = 4b*4h*64*64
  int bh = idx >> 12;                         // b*4 + h
  int de = idx & 4095;
  int b = bh >> 2, h = bh & 3;
  float s = 0.f;
#pragma unroll 4
  for (int p = 0; p < 128; ++p)
    s += bf2f(P[(((size_t)(b * 128 + p) * 4 + h) << 12) + de]);
  kv[idx] = s;
}

// ---------------- pass B1: M1T[b][o][j=h*64+d] = sum_e kv[b,h,d,e]/S * wo[o][h*64+e] ----------------
__global__ __launch_bounds__(256, 2)
void gka_m1(const float* __restrict__ kv, const unsigned short* __restrict__ wob,
            unsigned short* __restrict__ m1t) {
  const int tid = threadIdx.x;
  const int lane = tid & 63;
  const int wid = tid >> 6;               // wave -> o-range
  const int l15 = lane & 15, l4 = lane >> 4;
  const int blk = blockIdx.x;             // 16 = 4b x 4h
  const int b = blk >> 2, h = blk & 3;
  const float invS = 1.f / (float)SEQ;

  f32x4 acc[4][4];
#pragma unroll
  for (int m = 0; m < 4; ++m)
#pragma unroll
    for (int n = 0; n < 4; ++n) acc[m][n] = (f32x4)0.0f;

#pragma unroll
  for (int kk = 0; kk < 2; ++kk) {        // K = 64 (e)
    bf16x8 af[4], bw[4];
#pragma unroll
    for (int m = 0; m < 4; ++m) {
      int d = m * 16 + l15;
      int e0 = kk * 32 + l4 * 8;
      const f32x4* p = (const f32x4*)(kv + (size_t)((b * 4 + h) * 64 + d) * 64 + e0);
      f32x4 f0 = p[0], f1 = p[1];
      bf16x8 v;
      v[0] = f2bf(f0[0] * invS); v[1] = f2bf(f0[1] * invS);
      v[2] = f2bf(f0[2] * invS); v[3] = f2bf(f0[3] * invS);
      v[4] = f2bf(f1[0] * invS); v[5] = f2bf(f1[1] * invS);
      v[6] = f2bf(f1[2] * invS); v[7] = f2bf(f1[3] * invS);
      af[m] = v;
    }
#pragma unroll
    for (int n = 0; n < 4; ++n) {
      int o = wid * 64 + n * 16 + l15;
      int j = h * 64 + kk * 32 + l4 * 8;
      bw[n] = *(const bf16x8*)(wob + o * 256 + j);
    }
#pragma unroll
    for (int m = 0; m < 4; ++m)
#pragma unroll
      for (int n = 0; n < 4; ++n)
        acc[m][n] = MFMA16(af[m], bw[n], acc[m][n]);
  }
#pragma unroll
  for (int m = 0; m < 4; ++m)
#pragma unroll
    for (int n = 0; n < 4; ++n) {
      int o = wid * 64 + n * 16 + l15;
      int j0 = h * 64 + m * 16 + l4 * 4;
      bf16x4 pk;
#pragma unroll
      for (int r = 0; r < 4; ++r) pk[r] = f2bf(acc[m][n][r]);
      *(bf16x4*)(m1t + (size_t)(b * 256 + o) * 256 + j0) = pk;
    }
}

// ---------------- pass B2: WcT[b][o][i] = sum_j wqT[i][j] * M1T[b][o][j] ----------------
__global__ __launch_bounds__(512, 2)
void gka_wc(const unsigned short* __restrict__ wqt, const unsigned short* __restrict__ m1t,
            unsigned short* __restrict__ wct) {
  const int tid = threadIdx.x;
  const int lane = tid & 63;
  const int wid = tid >> 6;               // 8 waves: 2M x 4N
  const int wm = wid >> 2, wn = wid & 3;
  const int l15 = lane & 15, l4 = lane >> 4;
  const int blk = blockIdx.x;             // 8 = 4b x 2 i-half
  const int b = blk >> 1, ih = blk & 1;

  f32x4 acc[4][4];
#pragma unroll
  for (int m = 0; m < 4; ++m)
#pragma unroll
    for (int n = 0; n < 4; ++n) acc[m][n] = (f32x4)0.0f;

#pragma unroll
  for (int kk = 0; kk < 8; ++kk) {        // K = 256 (j)
    bf16x8 af[4], bw[4];
#pragma unroll
    for (int m = 0; m < 4; ++m) {
      int i = ih * 128 + wm * 64 + m * 16 + l15;
      af[m] = *(const bf16x8*)(wqt + i * 256 + kk * 32 + l4 * 8);
    }
#pragma unroll
    for (int n = 0; n < 4; ++n) {
      int o = wn * 64 + n * 16 + l15;
      bw[n] = *(const bf16x8*)(m1t + (size_t)(b * 256 + o) * 256 + kk * 32 + l4 * 8);
    }
#pragma unroll
    for (int m = 0; m < 4; ++m)
#pragma unroll
      for (int n = 0; n < 4; ++n)
        acc[m][n] = MFMA16(af[m], bw[n], acc[m][n]);
  }
#pragma unroll
  for (int m = 0; m < 4; ++m)
#pragma unroll
    for (int n = 0; n < 4; ++n) {
      int o = wn * 64 + n * 16 + l15;
      int i0 = ih * 128 + wm * 64 + m * 16 + l4 * 4;
      bf16x4 pk;
#pragma unroll
      for (int r = 0; r < 4; ++r) pk[r] = f2bf(acc[m][n][r]);
      *(bf16x4*)(wct + (size_t)(b * 256 + o) * 256 + i0) = pk;
    }
}

// ---------------- pass C: out = seq @ Wc[b] + bo ----------------
__global__ __launch_bounds__(256, 2)
void gka_out(const float* __restrict__ seq, const unsigned short* __restrict__ wct,
             const float* __restrict__ bo, float* __restrict__ out) {
  __shared__ char smem[32768];
  const int tid = threadIdx.x;
  const int lane = tid & 63;
  const int wid = tid >> 6;               // wave -> o-range (64 cols)
  const int l15 = lane & 15, l4 = lane >> 4, l7 = lane & 7;
  const int tile = blockIdx.x;
  const int b = tile >> 7;
  const int srow = (tile & 127) * 64;

  stage_x(smem, seq + (size_t)(b * SEQ + srow) * EMBED, tid);

  const unsigned short* W = wct + (size_t)b * 65536;   // WcT[b][o][i]
  float bov[4];
#pragma unroll
  for (int n = 0; n < 4; ++n) bov[n] = bo[wid * 64 + n * 16 + l15];

  f32x4 acc[4][4];
#pragma unroll
  for (int m = 0; m < 4; ++m)
#pragma unroll
    for (int n = 0; n < 4; ++n) acc[m][n] = (f32x4)0.0f;

  __syncthreads();

#pragma unroll
  for (int kk = 0; kk < 8; ++kk) {        // K = 256, no barriers
    bf16x8 af[4], bw[4];
#pragma unroll
    for (int m = 0; m < 4; ++m) {
      int row = m * 16 + l15;
      af[m] = *(const bf16x8*)(smem + row * 512 + ((kk * 64 + l4 * 16) ^ (l7 << 4)));
    }
#pragma unroll
    for (int n = 0; n < 4; ++n) {
      int row = wid * 64 + n * 16 + l15;   // o row of WcT (L2-resident)
      bw[n] = *(const bf16x8*)(W + row * 256 + kk * 32 + l4 * 8);
    }
#pragma unroll
    for (int m = 0; m < 4; ++m)
#pragma unroll
      for (int n = 0; n < 4; ++n)
        acc[m][n] = MFMA16(af[m], bw[n], acc[m][n]);
  }

  float* dst = out + (size_t)(b * SEQ + srow) * EMBED;
#pragma unroll
  for (int m = 0; m < 4; ++m)
#pragma unroll
    for (int n = 0; n < 4; ++n)
#pragma unroll
      for (int r = 0; r < 4; ++r)
        dst[(size_t)(m * 16 + l4 * 4 + r) * EMBED + wid * 64 + n * 16 + l15] =
            acc[m][n][r] + bov[n];
}

extern "C" void kernel_launch(void* const* d_in, const int* in_sizes, int n_in,
                              void* d_out, int out_size, void* d_ws, size_t ws_size,
                              hipStream_t stream) {
  const float* seq = (const float*)d_in[0];
  const float* wq  = (const float*)d_in[1];
  const float* wk  = (const float*)d_in[2];
  const float* wv  = (const float*)d_in[3];
  const float* wo  = (const float*)d_in[4];
  const float* bo  = (const float*)d_in[5];
  const float* lkg = (const float*)d_in[6];
  const float* lkb = (const float*)d_in[7];
  const float* lvg = (const float*)d_in[8];
  const float* lvb = (const float*)d_in[9];
  float* out = (float*)d_out;
  char* ws = (char*)d_ws;

  unsigned short* wkb = (unsigned short*)(ws + 0);
  unsigned short* wvb = (unsigned short*)(ws + 131072);
  unsigned short* wqt = (unsigned short*)(ws + 262144);
  unsigned short* wob = (unsigned short*)(ws + 393216);
  float*          kv  = (float*)(ws + 524288);
  unsigned short* m1t = (unsigned short*)(ws + 786432);
  unsigned short* wct = (unsigned short*)(ws + 1310720);
  unsigned short* P   = (unsigned short*)d_out;   // 16.8MB partials, overwritten by gka_out

  gka_prep<<<1024, 256, 0, stream>>>(wq, wk, wv, wo, wkb, wvb, wqt, wob);
  gka_kv<<<512, 256, 0, stream>>>(seq, wkb, wvb, lkg, lkb, lvg, lvb, P);
  gka_red<<<256, 256, 0, stream>>>(P, kv);
  gka_m1<<<16, 256, 0, stream>>>(kv, wob, m1t);
  gka_wc<<<8, 512, 0, stream>>>(wqt, m1t, wct);
  gka_out<<<512, 256, 0, stream>>>(seq, wct, bo, out);
}

// Round 3
// 79.776 us; speedup vs baseline: 1.2223x; 1.2223x over previous
//
#include <hip/hip_runtime.h>
#include <stdint.h>

// Galerkin self-attention, fused:
//   out = seq @ (wq.T @ blockdiag_h(kv[b,h]) @ wo.T) + bo
//   kv[b,h] = (1/S) * LN(k)_h^T @ LN(v)_h,   k = seq@wk.T, v = seq@wv.T
// v3: no register-resident kln/vln (spill fix: LN results go straight to LDS),
//     fragment-major weight layouts (coalesced 512B wave loads),
//     coalesced fragment-order P stores + layout-agnostic reduce,
//     gka_out at 4 blocks/CU (1024x32-token tiles).
// ws layout (bytes):
//   0        wkf bf16 fragment-major [wid][kk][n][lane][8]
//   131072   wvf bf16 fragment-major
//   262144   wqT bf16 [256 i][256 j]
//   393216   wob bf16 [256 o][256 j]
//   524288   kvf f32 [4 b][4 h][4096 frag]   (fragment order, written by gka_red)
//   786432   M1T bf16 [4 b][256 o][256 j]
//   1310720  wcf bf16 fragment-major [b][wid][kk][n][lane][8]
// d_out doubles as scratch for P = bf16 partials [4 b][128 p][4 h][4096 frag]
// (16.8MB of the 33.5MB output buffer); gka_out fully overwrites d_out last.

#define EMBED 256
#define SEQ   8192
#define LN_EPS 1e-5f

using bf16x8 = __attribute__((ext_vector_type(8))) short;
using bf16x4 = __attribute__((ext_vector_type(4))) short;
using f32x4  = __attribute__((ext_vector_type(4))) float;

static __device__ __forceinline__ short f2bf(float f) {
  uint32_t x = __float_as_uint(f);
  uint32_t r = x + 0x7fffu + ((x >> 16) & 1u);   // RNE
  return (short)(r >> 16);
}
static __device__ __forceinline__ float bf2f(uint32_t u) {
  return __uint_as_float(u << 16);
}

#define MFMA16(a, b, c) __builtin_amdgcn_mfma_f32_16x16x32_bf16((a), (b), (c), 0, 0, 0)

// Stage ROWS x 256 fp32 rows -> bf16 LDS [ROWS][256], rows 512B, byte^=(row&7)<<4
template <int ROWS>
static __device__ __forceinline__ void stage_x(char* smem, const float* __restrict__ src, int tid) {
#pragma unroll
  for (int i = 0; i < ROWS / 8; ++i) {
    int g = tid + i * 256;              // 16B-granule index
    int row = g >> 5, c16 = g & 31;
    const f32x4* p = (const f32x4*)(src + row * EMBED + c16 * 8);
    f32x4 f0 = p[0], f1 = p[1];
    bf16x8 v;
    v[0] = f2bf(f0[0]); v[1] = f2bf(f0[1]); v[2] = f2bf(f0[2]); v[3] = f2bf(f0[3]);
    v[4] = f2bf(f1[0]); v[5] = f2bf(f1[1]); v[6] = f2bf(f1[2]); v[7] = f2bf(f1[3]);
    *(bf16x8*)(smem + row * 512 + ((c16 * 16) ^ ((row & 7) << 4))) = v;
  }
}

// ---------------- prep: weights -> bf16 (wk/wv fragment-major, wq transposed) --------
__global__ void gka_prep(const float* __restrict__ wq, const float* __restrict__ wk,
                         const float* __restrict__ wv, const float* __restrict__ wo,
                         unsigned short* __restrict__ wkf, unsigned short* __restrict__ wvf,
                         unsigned short* __restrict__ wqt, unsigned short* __restrict__ wob) {
  int blk = blockIdx.x, tid = threadIdx.x;
  if (blk < 64) {                         // wk/wv -> fragment-major bf16x8 per thread
    int g = (blk & 31) * 256 + tid;       // [0, 8192)
    const float* W = (blk < 32) ? wk : wv;
    unsigned short* D = (blk < 32) ? wkf : wvf;
    int wid = g >> 11, kk = (g >> 8) & 7, n = (g >> 6) & 3, ln = g & 63;
    int row = wid * 64 + n * 16 + (ln & 15);
    int c0 = kk * 32 + (ln >> 4) * 8;
    const f32x4* p = (const f32x4*)(W + row * 256 + c0);
    f32x4 f0 = p[0], f1 = p[1];
    bf16x8 v;
    v[0] = f2bf(f0[0]); v[1] = f2bf(f0[1]); v[2] = f2bf(f0[2]); v[3] = f2bf(f0[3]);
    v[4] = f2bf(f1[0]); v[5] = f2bf(f1[1]); v[6] = f2bf(f1[2]); v[7] = f2bf(f1[3]);
    *(bf16x8*)(D + g * 8) = v;
  } else if (blk < 320) {                 // wq -> wqT
    int e = (blk - 64) * 256 + tid;
    int i = e >> 8, j = e & 255;
    wqt[e] = (unsigned short)f2bf(wq[j * 256 + i]);
  } else {                                // wo -> bf16
    int e = (blk - 320) * 256 + tid;
    wob[e] = (unsigned short)f2bf(wo[e]);
  }
}

// ---------------- pass A: k,v GEMM + per-head LN + per-tile kv partial ----------------
__global__ __launch_bounds__(256, 2)
void gka_kv(const float* __restrict__ seq,
            const unsigned short* __restrict__ wkf, const unsigned short* __restrict__ wvf,
            const float* __restrict__ lkg, const float* __restrict__ lkb,
            const float* __restrict__ lvg, const float* __restrict__ lvb,
            unsigned short* __restrict__ P) {
  __shared__ char smem[65536];            // [0,32K): x, later vT; [32K,64K): kT
  const int tid = threadIdx.x;
  const int lane = tid & 63;
  const int wid = tid >> 6;               // wave = head
  const int l15 = lane & 15, l4 = lane >> 4, l7 = lane & 7;
  const int tile = blockIdx.x;            // 512 blocks, 64 tokens each
  const int b = tile >> 7;
  const int ptile = tile & 127;

  stage_x<64>(smem, seq + (size_t)(b * SEQ + ptile * 64) * EMBED, tid);
  __syncthreads();

  // two GEMM+LN passes: mat0 = k -> kT @ smem+32K, mat1 = v -> vT @ smem (over x)
#pragma unroll
  for (int mat = 0; mat < 2; ++mat) {
    const unsigned short* Wf = mat ? wvf : wkf;
    const float* gp = mat ? lvg : lkg;
    const float* bp = mat ? lvb : lkb;
    float gv[4], bv[4];
#pragma unroll
    for (int n = 0; n < 4; ++n) { gv[n] = gp[n * 16 + l15]; bv[n] = bp[n * 16 + l15]; }

    f32x4 acc[4][4];
#pragma unroll
    for (int m = 0; m < 4; ++m)
#pragma unroll
      for (int n = 0; n < 4; ++n) acc[m][n] = (f32x4)0.0f;

#pragma unroll
    for (int kk = 0; kk < 8; ++kk) {      // K = 256, steps of 32
      bf16x8 af[4], bw[4];
#pragma unroll
      for (int m = 0; m < 4; ++m) {
        int row = m * 16 + l15;
        af[m] = *(const bf16x8*)(smem + row * 512 + ((kk * 64 + l4 * 16) ^ (l7 << 4)));
      }
#pragma unroll
      for (int n = 0; n < 4; ++n)         // fragment-major: 512B coalesced per wave
        bw[n] = *(const bf16x8*)(Wf + ((((wid * 8 + kk) * 4 + n) * 64 + lane) << 3));
#pragma unroll
      for (int m = 0; m < 4; ++m)
#pragma unroll
        for (int n = 0; n < 4; ++n)
          acc[m][n] = MFMA16(af[m], bw[n], acc[m][n]);
    }

    if (mat == 1) __syncthreads();        // all x-tile reads done; vT may overwrite x

    // LN over this wave's 64 head-cols, write transposed tile straight to LDS
    char* T = smem + (mat ? 0 : 32768) + wid * 8192;   // [64 d|e][64 s] bf16, 128B rows
#pragma unroll
    for (int m = 0; m < 4; ++m) {
      float mu[4], rs[4];
#pragma unroll
      for (int r = 0; r < 4; ++r) {
        float s1 = 0.f, s2 = 0.f;
#pragma unroll
        for (int n = 0; n < 4; ++n) { float x = acc[m][n][r]; s1 += x; s2 += x * x; }
#pragma unroll
        for (int msk = 1; msk < 16; msk <<= 1) {
          s1 += __shfl_xor(s1, msk);
          s2 += __shfl_xor(s2, msk);
        }
        mu[r] = s1 * (1.f / 64.f);
        float var = s2 * (1.f / 64.f) - mu[r] * mu[r];
        rs[r] = rsqrtf(var + LN_EPS);
      }
#pragma unroll
      for (int n = 0; n < 4; ++n) {
        bf16x4 pk;
#pragma unroll
        for (int r = 0; r < 4; ++r)
          pk[r] = f2bf((acc[m][n][r] - mu[r]) * rs[r] * gv[n] + bv[n]);
        int d = n * 16 + l15;             // d&7 == l7
        int sb = m * 32 + l4 * 8;         // byte offset of s0 = m*16+l4*4
        *(bf16x4*)(T + d * 128 + (sb ^ (l7 << 4))) = pk;
      }
    }
  }

  __syncthreads();                        // kT + vT ready

  // kv outer product: wave = head; kv[d][e] += sum_s kT[d][s] * vT[e][s]
  f32x4 a2[4][4];
#pragma unroll
  for (int fd = 0; fd < 4; ++fd)
#pragma unroll
    for (int n = 0; n < 4; ++n) a2[fd][n] = (f32x4)0.0f;

#pragma unroll
  for (int kk = 0; kk < 2; ++kk) {        // 64 tokens = 2 K-steps
    bf16x8 ak[4], bv2[4];
#pragma unroll
    for (int fd = 0; fd < 4; ++fd) {
      int d = fd * 16 + l15;
      ak[fd] = *(const bf16x8*)(smem + 32768 + wid * 8192 + d * 128 +
                                ((kk * 64 + l4 * 16) ^ (l7 << 4)));
    }
#pragma unroll
    for (int n = 0; n < 4; ++n) {
      int e = n * 16 + l15;
      bv2[n] = *(const bf16x8*)(smem + wid * 8192 + e * 128 +
                                ((kk * 64 + l4 * 16) ^ (l7 << 4)));
    }
#pragma unroll
    for (int fd = 0; fd < 4; ++fd)
#pragma unroll
      for (int n = 0; n < 4; ++n)
        a2[fd][n] = MFMA16(ak[fd], bv2[n], a2[fd][n]);
  }

  // store P in raw fragment order: flat = (fd*4+n)*256 + lane*4 + r  (coalesced 512B)
  unsigned short* Ph = P + ((size_t)((b * 128 + ptile) * 4 + wid) << 12);
#pragma unroll
  for (int fd = 0; fd < 4; ++fd)
#pragma unroll
    for (int n = 0; n < 4; ++n) {
      bf16x4 pk;
#pragma unroll
      for (int r = 0; r < 4; ++r) pk[r] = f2bf(a2[fd][n][r]);
      *(bf16x4*)(Ph + (fd * 4 + n) * 256 + lane * 4) = pk;
    }
}

// ---------------- reduce: kvf[b,h,flat] = sum_p P[b,p,h,flat]  (layout-agnostic) -----
__global__ __launch_bounds__(128)
void gka_red(const unsigned short* __restrict__ P, float* __restrict__ kvf) {
  int q = blockIdx.x * 128 + threadIdx.x;   // 16384 quads of 4 elems
  int b = q >> 12, h = (q >> 10) & 3, t4 = q & 1023;
  const unsigned short* p0 = P + ((size_t)(b * 128) * 4 + h) * 4096 + t4 * 4;
  float s0 = 0.f, s1 = 0.f, s2 = 0.f, s3 = 0.f;
#pragma unroll 4
  for (int p = 0; p < 128; ++p) {
    uint2 u = *(const uint2*)(p0 + (size_t)p * 16384);
    s0 += bf2f(u.x & 0xffffu); s1 += bf2f(u.x >> 16);
    s2 += bf2f(u.y & 0xffffu); s3 += bf2f(u.y >> 16);
  }
  f32x4 r; r[0] = s0; r[1] = s1; r[2] = s2; r[3] = s3;
  *(f32x4*)(kvf + ((b * 4 + h) << 12) + t4 * 4) = r;
}

// ---------------- pass B1: M1T[b][o][j=h*64+d] = sum_e kv[d][e]/S * wo[o][h*64+e] ----
__global__ __launch_bounds__(256, 2)
void gka_m1(const float* __restrict__ kvf, const unsigned short* __restrict__ wob,
            unsigned short* __restrict__ m1t) {
  const int tid = threadIdx.x;
  const int lane = tid & 63;
  const int wid = tid >> 6;               // wave -> o-range
  const int l15 = lane & 15, l4 = lane >> 4;
  const int blk = blockIdx.x;             // 16 = 4b x 4h
  const int b = blk >> 2, h = blk & 3;
  const float invS = 1.f / (float)SEQ;
  const float* kvh = kvf + ((b * 4 + h) << 12);

  f32x4 acc[4][4];
#pragma unroll
  for (int m = 0; m < 4; ++m)
#pragma unroll
    for (int n = 0; n < 4; ++n) acc[m][n] = (f32x4)0.0f;

#pragma unroll
  for (int kk = 0; kk < 2; ++kk) {        // K = 64 (e)
    bf16x8 af[4], bw[4];
#pragma unroll
    for (int m = 0; m < 4; ++m) {
      // gather (d = m*16+l15, e = kk*32+l4*8+j) from fragment layout
      int base = (m * 4 + kk * 2 + (l4 >> 1)) * 256 +
                 ((l15 >> 2) * 16 + (l4 & 1) * 8) * 4 + (l15 & 3);
      bf16x8 v;
#pragma unroll
      for (int j = 0; j < 8; ++j) v[j] = f2bf(kvh[base + j * 4] * invS);
      af[m] = v;
    }
#pragma unroll
    for (int n = 0; n < 4; ++n) {
      int o = wid * 64 + n * 16 + l15;
      bw[n] = *(const bf16x8*)(wob + o * 256 + h * 64 + kk * 32 + l4 * 8);
    }
#pragma unroll
    for (int m = 0; m < 4; ++m)
#pragma unroll
      for (int n = 0; n < 4; ++n)
        acc[m][n] = MFMA16(af[m], bw[n], acc[m][n]);
  }
#pragma unroll
  for (int m = 0; m < 4; ++m)
#pragma unroll
    for (int n = 0; n < 4; ++n) {
      int o = wid * 64 + n * 16 + l15;
      int j0 = h * 64 + m * 16 + l4 * 4;
      bf16x4 pk;
#pragma unroll
      for (int r = 0; r < 4; ++r) pk[r] = f2bf(acc[m][n][r]);
      *(bf16x4*)(m1t + (size_t)(b * 256 + o) * 256 + j0) = pk;
    }
}

// ---------------- pass B2: wcf = fragment-major WcT; Wc[i][o] = sum_j wqT[i][j]*M1T[o][j]
__global__ __launch_bounds__(512, 2)
void gka_wc(const unsigned short* __restrict__ wqt, const unsigned short* __restrict__ m1t,
            unsigned short* __restrict__ wcf) {
  const int tid = threadIdx.x;
  const int lane = tid & 63;
  const int wid = tid >> 6;               // 8 waves: 2M x 4N
  const int wm = wid >> 2, wn = wid & 3;
  const int l15 = lane & 15, l4 = lane >> 4;
  const int blk = blockIdx.x;             // 8 = 4b x 2 i-half
  const int b = blk >> 1, ih = blk & 1;

  f32x4 acc[4][4];
#pragma unroll
  for (int m = 0; m < 4; ++m)
#pragma unroll
    for (int n = 0; n < 4; ++n) acc[m][n] = (f32x4)0.0f;

#pragma unroll
  for (int kk = 0; kk < 8; ++kk) {        // K = 256 (j)
    bf16x8 af[4], bw[4];
#pragma unroll
    for (int m = 0; m < 4; ++m) {
      int i = ih * 128 + wm * 64 + m * 16 + l15;
      af[m] = *(const bf16x8*)(wqt + i * 256 + kk * 32 + l4 * 8);
    }
#pragma unroll
    for (int n = 0; n < 4; ++n) {
      int o = wn * 64 + n * 16 + l15;
      bw[n] = *(const bf16x8*)(m1t + (size_t)(b * 256 + o) * 256 + kk * 32 + l4 * 8);
    }
#pragma unroll
    for (int m = 0; m < 4; ++m)
#pragma unroll
      for (int n = 0; n < 4; ++n)
        acc[m][n] = MFMA16(af[m], bw[n], acc[m][n]);
  }
  // store to fragment-major wcf for gka_out: elem (o, i): 
  // flat = (((o>>6)*8 + (i>>5))*4 + ((o>>4)&3))*64*8 + (((i>>3)&3)*16 + (o&15))*8 + (i&7)
#pragma unroll
  for (int m = 0; m < 4; ++m)
#pragma unroll
    for (int n = 0; n < 4; ++n) {
      int kko = ih * 4 + wm * 2 + (m >> 1);
      int laneo = ((m & 1) * 2 + (l4 >> 1)) * 16 + l15;
      int jo = (l4 & 1) * 4;
      bf16x4 pk;
#pragma unroll
      for (int r = 0; r < 4; ++r) pk[r] = f2bf(acc[m][n][r]);
      *(bf16x4*)(wcf + ((size_t)b << 16) +
                 (((((wn * 8 + kko) * 4 + n) * 64) + laneo) << 3) + jo) = pk;
    }
}

// ---------------- pass C: out = seq @ Wc[b] + bo  (1024 x 32-token tiles) ------------
__global__ __launch_bounds__(256, 4)
void gka_out(const float* __restrict__ seq, const unsigned short* __restrict__ wcf,
             const float* __restrict__ bo, float* __restrict__ out) {
  __shared__ char smem[16384];
  const int tid = threadIdx.x;
  const int lane = tid & 63;
  const int wid = tid >> 6;               // wave -> o-range (64 cols)
  const int l15 = lane & 15, l4 = lane >> 4, l7 = lane & 7;
  const int tile = blockIdx.x;            // 1024 = 4b x 256 tiles of 32 rows
  const int b = tile >> 8;
  const int srow = (tile & 255) * 32;

  stage_x<32>(smem, seq + (size_t)(b * SEQ + srow) * EMBED, tid);

  const unsigned short* Wf = wcf + ((size_t)b << 16);
  float bov[4];
#pragma unroll
  for (int n = 0; n < 4; ++n) bov[n] = bo[wid * 64 + n * 16 + l15];

  f32x4 acc[2][4];
#pragma unroll
  for (int m = 0; m < 2; ++m)
#pragma unroll
    for (int n = 0; n < 4; ++n) acc[m][n] = (f32x4)0.0f;

  __syncthreads();

#pragma unroll
  for (int kk = 0; kk < 8; ++kk) {        // K = 256
    bf16x8 af[2], bw[4];
#pragma unroll
    for (int m = 0; m < 2; ++m) {
      int row = m * 16 + l15;
      af[m] = *(const bf16x8*)(smem + row * 512 + ((kk * 64 + l4 * 16) ^ (l7 << 4)));
    }
#pragma unroll
    for (int n = 0; n < 4; ++n)           // coalesced 512B per wave
      bw[n] = *(const bf16x8*)(Wf + ((((wid * 8 + kk) * 4 + n) * 64 + lane) << 3));
#pragma unroll
    for (int m = 0; m < 2; ++m)
#pragma unroll
      for (int n = 0; n < 4; ++n)
        acc[m][n] = MFMA16(af[m], bw[n], acc[m][n]);
  }

  float* dst = out + (size_t)(b * SEQ + srow) * EMBED;
#pragma unroll
  for (int m = 0; m < 2; ++m)
#pragma unroll
    for (int n = 0; n < 4; ++n)
#pragma unroll
      for (int r = 0; r < 4; ++r)
        dst[(size_t)(m * 16 + l4 * 4 + r) * EMBED + wid * 64 + n * 16 + l15] =
            acc[m][n][r] + bov[n];
}

extern "C" void kernel_launch(void* const* d_in, const int* in_sizes, int n_in,
                              void* d_out, int out_size, void* d_ws, size_t ws_size,
                              hipStream_t stream) {
  const float* seq = (const float*)d_in[0];
  const float* wq  = (const float*)d_in[1];
  const float* wk  = (const float*)d_in[2];
  const float* wv  = (const float*)d_in[3];
  const float* wo  = (const float*)d_in[4];
  const float* bo  = (const float*)d_in[5];
  const float* lkg = (const float*)d_in[6];
  const float* lkb = (const float*)d_in[7];
  const float* lvg = (const float*)d_in[8];
  const float* lvb = (const float*)d_in[9];
  float* out = (float*)d_out;
  char* ws = (char*)d_ws;

  unsigned short* wkf = (unsigned short*)(ws + 0);
  unsigned short* wvf = (unsigned short*)(ws + 131072);
  unsigned short* wqt = (unsigned short*)(ws + 262144);
  unsigned short* wob = (unsigned short*)(ws + 393216);
  float*          kvf = (float*)(ws + 524288);
  unsigned short* m1t = (unsigned short*)(ws + 786432);
  unsigned short* wcf = (unsigned short*)(ws + 1310720);
  unsigned short* P   = (unsigned short*)d_out;   // 16.8MB partials, overwritten by gka_out

  gka_prep<<<576, 256, 0, stream>>>(wq, wk, wv, wo, wkf, wvf, wqt, wob);
  gka_kv<<<512, 256, 0, stream>>>(seq, wkf, wvf, lkg, lkb, lvg, lvb, P);
  gka_red<<<128, 128, 0, stream>>>(P, kvf);
  gka_m1<<<16, 256, 0, stream>>>(kvf, wob, m1t);
  gka_wc<<<8, 512, 0, stream>>>(wqt, m1t, wcf);
  gka_out<<<1024, 256, 0, stream>>>(seq, wcf, bo, out);
}